// Round 2
// baseline (22.374 us; speedup 1.0000x reference)
//
#include <hip/hip_runtime.h>
#include <hip/hip_bf16.h>

// FrameReducer: N=16, T=2048, C=512, V=500
//
// Stage A (mask_kernel): grid = N*T/256 blocks x 256 threads. Each wave
//   evaluates 64 t's: keep[t] = (ctc[n,t,blank] < log(0.9)) && (t < x_lens[n]).
//   __ballot -> ws masks[N][32] (uint64) + counts[N][32] (popcount).
// Stage B (gather_kernel): one block per output row (n,p), 128 threads.
//   Thread 0 builds the exclusive prefix of counts[n][*] in LDS (32 adds,
//   L2-resident). Each block then locates its source t = (p-th set bit across
//   the 32 mask words) via 5-step binary search on the prefix + 6-step
//   k-th-set-bit within the 64-bit word, and copies the 2KB row float4-wide.
//   Rows with p >= lens write zeros (required: harness never re-poisons).
//   p==0 blocks write lens_out[n] (float) to the tail of d_out.

__global__ void mask_kernel(const float* __restrict__ ctc,
                            const void* __restrict__ x_lens_raw,
                            const int* __restrict__ blank_id_p,
                            int T, int V, int N,
                            unsigned long long* __restrict__ masks,
                            int* __restrict__ counts) {
    const int g = blockIdx.x * 256 + threadIdx.x;   // global t index across [N*T]
    const int n = g / T;
    const int t = g % T;
    const int lane = threadIdx.x & 63;

    // x_lens dtype detection: values in [1,T], never 0 -> int64 layout iff
    // the int32 view at odd index is 0.
    const int* li = (const int*)x_lens_raw;
    long long L;
    if (N > 1 && li[1] == 0) {
        L = ((const long long*)x_lens_raw)[n];
    } else {
        L = (long long)li[n];
    }

    const int blank = *blank_id_p;
    const float thr = -0.10536052f;                 // float32(log(0.9))

    float v = ctc[((long long)n * T + t) * V + blank];
    bool keep = (v < thr) && ((long long)t < L);

    unsigned long long bal = __ballot(keep);
    if (lane == 0) {
        int chunk = t >> 6;                          // 0..T/64-1 (32)
        masks[n * (T >> 6) + chunk] = bal;
        counts[n * (T >> 6) + chunk] = __popcll(bal);
    }
}

__global__ void gather_kernel(const float* __restrict__ x,
                              const unsigned long long* __restrict__ masks,
                              const int* __restrict__ counts,
                              float* __restrict__ out,
                              float* __restrict__ lens_out,
                              int Tp, int T, int C) {
    const int NCHUNK = T >> 6;                       // 32
    const long long row = blockIdx.x;                // n*Tp + p
    const int n = (int)(row / Tp);
    const int p = (int)(row % Tp);
    const int tid = threadIdx.x;                     // 128 threads

    extern __shared__ int prefix[];                  // NCHUNK+1 ints
    if (tid == 0) {
        int acc = 0;
        const int* cn = counts + n * NCHUNK;
        for (int c = 0; c < NCHUNK; ++c) { prefix[c] = acc; acc += cn[c]; }
        prefix[NCHUNK] = acc;
    }
    __syncthreads();
    const int lens = prefix[NCHUNK];

    if (p == 0 && tid == 0) lens_out[n] = (float)lens;

    float4 v = make_float4(0.f, 0.f, 0.f, 0.f);
    if (p < lens) {
        // binary search: largest c with prefix[c] <= p
        int lo = 0, hi = NCHUNK;
        while (hi - lo > 1) {
            int mid = (lo + hi) >> 1;
            if (prefix[mid] <= p) lo = mid; else hi = mid;
        }
        int r = p - prefix[lo];
        unsigned long long m = masks[n * NCHUNK + lo];
        int base = 0;
        #pragma unroll
        for (int w = 32; w >= 1; w >>= 1) {
            int cnt = __popcll(m & ((1ull << w) - 1ull));
            if (r >= cnt) { r -= cnt; m >>= w; base += w; }
        }
        int tsrc = (lo << 6) + base;
        const float4* src = (const float4*)(x + ((long long)n * T + tsrc) * C);
        v = src[tid];
    }
    float4* dst = (float4*)(out + row * (long long)C);
    dst[tid] = v;
}

extern "C" void kernel_launch(void* const* d_in, const int* in_sizes, int n_in,
                              void* d_out, int out_size, void* d_ws, size_t ws_size,
                              hipStream_t stream) {
    const float* x        = (const float*)d_in[0];
    const void*  x_lens   = d_in[1];
    const float* ctc      = (const float*)d_in[2];
    const int*   blank_id = (const int*)d_in[3];

    const int N = in_sizes[1];               // 16
    const int C = 512;
    const int V = 500;
    const int T = in_sizes[0] / (N * C);     // 2048
    const int Tp = (out_size - N) / (N * C); // T'
    const int NCHUNK = T >> 6;               // 32

    unsigned long long* masks = (unsigned long long*)d_ws;       // [N][32]
    int* counts = (int*)(masks + (long long)N * NCHUNK);         // [N][32]

    float* out      = (float*)d_out;                             // [N][Tp][C]
    float* lens_out = out + (long long)N * Tp * C;               // [N] float

    mask_kernel<<<(N * T) / 256, 256, 0, stream>>>(ctc, x_lens, blank_id, T, V, N, masks, counts);
    gather_kernel<<<(unsigned int)(N * Tp), C / 4, (NCHUNK + 1) * sizeof(int), stream>>>(
        x, masks, counts, out, lens_out, Tp, T, C);
}

// Round 3
// 18.845 us; speedup vs baseline: 1.1872x; 1.1872x over previous
//
#include <hip/hip_runtime.h>
#include <hip/hip_bf16.h>

// FrameReducer: N=16, T=2048, C=512, V=500
//
// Kernel 1 (compact): N blocks x 1024 threads. Per block (sequence n):
//   keep[t] = (ctc[n,t,blank] < log(0.9)) && (t < x_lens[n])
//   wave __ballot -> per-64-chunk counts in LDS -> exclusive block scan
//   (serial by t0 over <=64 entries, once per block) -> each kept thread
//   emits idx[n*T + pos] = t (stable order). Writes lens[n] and the float
//   lens tail of d_out.
// Kernel 2 (gather): flat over all output float4s. Thread gid ->
//   row = gid>>cshift (cshift=log2(C/4)), n = row/Tp, p = row%Tp.
//   out f4 = (p < lens[n]) ? x[n, idx[n*T+p], :] f4 : 0.
//   lens/idx loads are uniform per row-group -> L1 broadcast.

__global__ void compact_kernel(const float* __restrict__ ctc,
                               const void* __restrict__ x_lens_raw,
                               const int* __restrict__ blank_id_p,
                               int T, int V, int N,
                               int* __restrict__ idx,
                               int* __restrict__ lens,
                               float* __restrict__ lens_out) {
    const int n    = blockIdx.x;
    const int tid  = threadIdx.x;          // 1024 threads = 16 waves
    const int lane = tid & 63;
    const int wid  = tid >> 6;
    const int ITERS = (T + 1023) >> 10;    // 2 for T=2048
    const int NCHUNK = ITERS * 16;         // 32

    __shared__ int wcnt[64];
    __shared__ int pfx[65];

    // x_lens dtype detection: values in [1,T], never 0 -> int64 layout iff
    // int32 view at odd index is 0.
    const int* li = (const int*)x_lens_raw;
    long long L;
    if (N > 1 && li[1] == 0) {
        L = ((const long long*)x_lens_raw)[n];
    } else {
        L = (long long)li[n];
    }

    const int blank = *blank_id_p;
    const float thr = -0.10536052f;        // float32(log(0.9))

    unsigned long long bal[4];             // per-iteration ballot (ITERS<=4)
    #pragma unroll
    for (int j = 0; j < 4; ++j) bal[j] = 0ull;

    for (int j = 0; j < ITERS; ++j) {
        int t = (j << 10) + tid;
        bool keep = false;
        if (t < T) {
            float v = ctc[((long long)n * T + t) * V + blank];
            keep = (v < thr) && ((long long)t < L);
        }
        bal[j] = __ballot(keep);
        if (lane == 0) wcnt[j * 16 + wid] = __popcll(bal[j]);
    }
    __syncthreads();

    if (tid == 0) {
        int acc = 0;
        for (int c = 0; c < NCHUNK; ++c) { pfx[c] = acc; acc += wcnt[c]; }
        pfx[NCHUNK] = acc;
        lens[n] = acc;
        lens_out[n] = (float)acc;
    }
    __syncthreads();

    int* my_idx = idx + (long long)n * T;
    for (int j = 0; j < ITERS; ++j) {
        int t = (j << 10) + tid;
        unsigned long long b = bal[j];
        if (b & (1ull << lane)) {
            int rank = __popcll(b & ((1ull << lane) - 1ull));
            my_idx[pfx[j * 16 + wid] + rank] = t;
        }
    }
}

__global__ void gather_kernel(const float* __restrict__ x,
                              const int* __restrict__ idx,
                              const int* __restrict__ lens,
                              float* __restrict__ out,
                              int Tp, int T, int cshift, int total_f4) {
    const int gid = blockIdx.x * blockDim.x + threadIdx.x;
    if (gid >= total_f4) return;
    const int row = gid >> cshift;         // n*Tp + p
    const int c4  = gid & ((1 << cshift) - 1);
    const int n = row / Tp;
    const int p = row - n * Tp;

    float4 v = make_float4(0.f, 0.f, 0.f, 0.f);
    if (p < lens[n]) {
        int tsrc = idx[n * T + p];
        const float4* src = (const float4*)(x + ((long long)(n * T + tsrc) << (cshift + 2)));
        v = src[c4];
    }
    ((float4*)out)[gid] = v;
}

extern "C" void kernel_launch(void* const* d_in, const int* in_sizes, int n_in,
                              void* d_out, int out_size, void* d_ws, size_t ws_size,
                              hipStream_t stream) {
    const float* x        = (const float*)d_in[0];
    const void*  x_lens   = d_in[1];
    const float* ctc      = (const float*)d_in[2];
    const int*   blank_id = (const int*)d_in[3];

    const int N = in_sizes[1];               // 16
    const int C = 512;
    const int V = 500;
    const int T = in_sizes[0] / (N * C);     // 2048
    const int Tp = (out_size - N) / (N * C); // T'
    const int cshift = 7;                    // log2(C/4) = log2(128)

    int* idx  = (int*)d_ws;                  // [N][T]
    int* lens = idx + (long long)N * T;      // [N]

    float* out      = (float*)d_out;                   // [N][Tp][C]
    float* lens_out = out + (long long)N * Tp * C;     // [N] float

    compact_kernel<<<N, 1024, 0, stream>>>(ctc, x_lens, blank_id, T, V, N,
                                           idx, lens, lens_out);

    const int total_f4 = N * Tp * (C / 4);
    const int blocks = (total_f4 + 255) / 256;
    gather_kernel<<<blocks, 256, 0, stream>>>(x, idx, lens, out, Tp, T, cshift, total_f4);
}